// Round 2
// baseline (182.854 us; speedup 1.0000x reference)
//
#include <hip/hip_runtime.h>

#define T_DIM 2048
#define B_DIM 16
#define C_DIM 512
#define NW 56            // H*K

// ---- fused-kernel (fallback) LDS map
#define XS_BYTES (22 * 512 * 2)       // bf16 x window, swizzled: 22528 B
#define A_OFF    XS_BYTES             // A-frag region (16 ks * 64 lanes * 16 B = 16384 B)
#define WT_OFF   (XS_BYTES + 4160)    // wt (fp32 16x56) lives after L (16x65x4 = 4160 B)
#define LDS_TOTAL (XS_BYTES + 16384)  // 38912 B

// ---- split-kernel LDS maps
#define W_L_OFF   16384               // L: 16x65 fp32 = 4160 B (after A8 16384 B)
#define W_WT_OFF  (16384 + 4160)      // wt: 16x56 fp32 = 3584 B
#define W_LDS     (16384 + 4160 + 3584)   // 24128 B
#define C_WT_OFF  XS_BYTES
#define C_LDS     (XS_BYTES + 3584)   // 26112 B -> 6 blocks/CU

typedef __attribute__((ext_vector_type(8))) short short8;
typedef __attribute__((ext_vector_type(4))) float floatx4;

static __device__ __forceinline__ unsigned short f2bf(float x) {
    union { float f; unsigned u; } v; v.f = x;
    return (unsigned short)((v.u + 0x7FFFu + ((v.u >> 16) & 1u)) >> 16);  // RNE
}
static __device__ __forceinline__ float bf_lo(unsigned u) {
    union { unsigned u; float f; } c; c.u = u << 16; return c.f;
}
static __device__ __forceinline__ float bf_hi(unsigned u) {
    union { unsigned u; float f; } c; c.u = u & 0xFFFF0000u; return c.f;
}
// 16B-block XOR swizzle for the bf16 xs layout: bank-group bits [6:4] ^= addr[9:7].
static __device__ __forceinline__ int swz(int a) { return a ^ ((a >> 3) & 0x70); }

// ---------------------------------------------------------------------------
// Pre-kernel: pack W (512x56 fp32) into bf16 MFMA B-fragments.
// ---------------------------------------------------------------------------
__global__ __launch_bounds__(256)
void pack_w(const float* __restrict__ W, short8* __restrict__ Bg) {
    const int g  = blockIdx.x * 256 + threadIdx.x;   // 0..4095
    const int ks = g >> 8;
    const int nt = (g >> 6) & 3;
    const int l  = g & 63;
    const int n  = nt * 16 + (l & 15);
    const int k0 = ks * 32 + ((l >> 4) & 3) * 8;
    short8 o;
#pragma unroll
    for (int j = 0; j < 8; ++j) {
        const float v = (n < NW) ? W[(size_t)(k0 + j) * NW + n] : 0.f;
        o[j] = (short)f2bf(v);
    }
    Bg[g] = o;
}

// ---------------------------------------------------------------------------
// Kernel W: logits GEMM + softmax -> wt_g[(t*B+b)*56 + h*7 + k] (fp32).
// Block = 16 t x 1 b, 4 waves; wave wv owns n-tile wv. Pure q-stream.
// ---------------------------------------------------------------------------
__global__ __launch_bounds__(256)
void weight_kernel(const float* __restrict__ q, const short8* __restrict__ Bg,
                   float* __restrict__ wt_g) {
    __shared__ __align__(16) char S[W_LDS];

    const int tid  = threadIdx.x;
    const int lane = tid & 63;
    const int wv   = tid >> 6;
    const int b    = blockIdx.x & 15;
    const int t0   = (blockIdx.x >> 4) * 16;

    // issue q loads: thread stages frags for ks in {wv, wv+4, wv+8, wv+12}
    const int rq = lane & 15;
    const int qq = lane >> 4;
    const float* qrow = q + ((size_t)(t0 + rq) * B_DIM + b) * C_DIM + qq * 8;
    float4 qr[4][2];
#pragma unroll
    for (int s = 0; s < 4; ++s) {
        const int ks = wv + s * 4;
        qr[s][0] = *(const float4*)(qrow + ks * 32);
        qr[s][1] = *(const float4*)(qrow + ks * 32 + 4);
    }
    // B-frag loads (L2-hot)
    short8 bfr[16];
#pragma unroll
    for (int ks = 0; ks < 16; ++ks)
        bfr[ks] = Bg[(ks * 4 + wv) * 64 + lane];

    // stage A tile in fragment order
    short8* A8 = (short8*)S;
#pragma unroll
    for (int s = 0; s < 4; ++s) {
        const int ks = wv + s * 4;
        short8 o;
        o[0] = (short)f2bf(qr[s][0].x); o[1] = (short)f2bf(qr[s][0].y);
        o[2] = (short)f2bf(qr[s][0].z); o[3] = (short)f2bf(qr[s][0].w);
        o[4] = (short)f2bf(qr[s][1].x); o[5] = (short)f2bf(qr[s][1].y);
        o[6] = (short)f2bf(qr[s][1].z); o[7] = (short)f2bf(qr[s][1].w);
        A8[ks * 64 + lane] = o;
    }
    __syncthreads();

    floatx4 acc = (floatx4){0.f, 0.f, 0.f, 0.f};
#pragma unroll
    for (int ks = 0; ks < 16; ++ks) {
        const short8 af = A8[ks * 64 + lane];
        acc = __builtin_amdgcn_mfma_f32_16x16x32_bf16(af, bfr[ks], acc, 0, 0, 0);
    }

    // logits -> L (separate region, no conflict with A8)
    float* L = (float*)(S + W_L_OFF);
    const int m = lane & 15;
    const int quad = lane >> 4;
#pragma unroll
    for (int r = 0; r < 4; ++r)
        L[(quad * 4 + r) * 65 + wv * 16 + m] = acc[r];
    __syncthreads();

    // softmax over groups of 7: 128 tasks -> wt (LDS)
    float* wt = (float*)(S + W_WT_OFF);
    if (tid < 128) {
        const int row = tid >> 3, h = tid & 7;
        const float* Lp = L + row * 65 + h * 7;
        float mx = Lp[0];
#pragma unroll
        for (int k = 1; k < 7; ++k) mx = fmaxf(mx, Lp[k]);
        float e[7], sm = 0.f;
#pragma unroll
        for (int k = 0; k < 7; ++k) { e[k] = __expf(Lp[k] - mx); sm += e[k]; }
        const float inv = 1.0f / sm;
#pragma unroll
        for (int k = 0; k < 7; ++k) wt[row * NW + h * 7 + k] = e[k] * inv;
    }
    __syncthreads();

    // cooperative coalesced write-out: 224 threads x float4 (16 rows x 14)
    if (tid < 224) {
        const int row = tid / 14;
        const int j   = tid - row * 14;
        const float4 v = *(const float4*)(wt + row * NW + j * 4);
        *(float4*)(wt_g + ((size_t)(t0 + row) * B_DIM + b) * NW + j * 4) = v;
    }
}

// ---------------------------------------------------------------------------
// Kernel C: conv with precomputed weights. Block = 16 t x 1 b, ONE sync.
// LDS = 26112 B -> 6 blocks/CU; __launch_bounds__(256,6) caps VGPR at 85.
// ---------------------------------------------------------------------------
__global__ __launch_bounds__(256, 6)
void conv_kernel(const float* __restrict__ x, const float* __restrict__ wt_g,
                 float* __restrict__ out) {
    __shared__ __align__(16) char S[C_LDS];

    const int tid  = threadIdx.x;
    const int lane = tid & 63;
    const int wv   = tid >> 6;
    const int b    = blockIdx.x & 15;
    const int t0   = (blockIdx.x >> 4) * 16;

    // issue x-window loads (22 padded rows x 512 fp32)
    float4 xr[11];
#pragma unroll
    for (int j = 0; j < 11; ++j) {
        const int idx = tid + j * 256;         // float4 index 0..2815
        const int i   = idx >> 7;              // padded row 0..21
        const int c   = (idx & 127) * 4;
        const int tp  = t0 + i - 3;
        xr[j] = make_float4(0.f, 0.f, 0.f, 0.f);
        if (tp >= 0 && tp < T_DIM)
            xr[j] = *(const float4*)(x + ((size_t)tp * B_DIM + b) * C_DIM + c);
    }
    // issue wt load (896 floats = 224 float4)
    const int row = tid / 14;
    const int jw  = tid - row * 14;
    float4 wld = make_float4(0.f, 0.f, 0.f, 0.f);
    if (tid < 224)
        wld = *(const float4*)(wt_g + ((size_t)(t0 + row) * B_DIM + b) * NW + jw * 4);

    // convert x -> bf16 xs (swizzled)
    char* XS = S;
#pragma unroll
    for (int j = 0; j < 11; ++j) {
        const int idx = tid + j * 256;
        uint2 p;
        p.x = (unsigned)f2bf(xr[j].x) | ((unsigned)f2bf(xr[j].y) << 16);
        p.y = (unsigned)f2bf(xr[j].z) | ((unsigned)f2bf(xr[j].w) << 16);
        *(uint2*)(XS + swz(idx * 8)) = p;
    }
    if (tid < 224)
        *(float4*)(S + C_WT_OFF + (row * NW + jw * 4) * 4) = wld;
    __syncthreads();

    // conv: lane owns outputs 8l..8l+8 = window bytes [112l, 112l+112)
    const float* wt = (const float*)(S + C_WT_OFF);
    const int h = lane >> 3;
    const int base_b = lane * 112;
#pragma unroll
    for (int s = 0; s < 4; ++s) {
        const int tt = wv * 4 + s;
        const int tb = tt * 1024 + base_b;
        uint4 xu[7];
#pragma unroll
        for (int i = 0; i < 7; ++i)
            xu[i] = *(const uint4*)(XS + swz(tb + i * 16));
        float xf[56];
#pragma unroll
        for (int i = 0; i < 7; ++i) {
            xf[i * 8 + 0] = bf_lo(xu[i].x); xf[i * 8 + 1] = bf_hi(xu[i].x);
            xf[i * 8 + 2] = bf_lo(xu[i].y); xf[i * 8 + 3] = bf_hi(xu[i].y);
            xf[i * 8 + 4] = bf_lo(xu[i].z); xf[i * 8 + 5] = bf_hi(xu[i].z);
            xf[i * 8 + 6] = bf_lo(xu[i].w); xf[i * 8 + 7] = bf_hi(xu[i].w);
        }
        const float* wp = wt + tt * NW + h * 7;
        float w[7];
#pragma unroll
        for (int k = 0; k < 7; ++k) w[k] = wp[k];
        float a8[8];
#pragma unroll
        for (int r = 0; r < 8; ++r) {
            float sacc = xf[r * 7] * w[0];
#pragma unroll
            for (int k = 1; k < 7; ++k) sacc = fmaf(w[k], xf[r * 7 + k], sacc);
            a8[r] = sacc;
        }
        float* orow = out + ((size_t)(t0 + tt) * B_DIM + b) * C_DIM + lane * 8;
        floatx4 v0 = (floatx4){a8[0], a8[1], a8[2], a8[3]};
        floatx4 v1 = (floatx4){a8[4], a8[5], a8[6], a8[7]};
        __builtin_nontemporal_store(v0, (floatx4*)orow);
        __builtin_nontemporal_store(v1, (floatx4*)(orow + 4));
    }
}

// ---------------------------------------------------------------------------
// Fallback: original fused kernel (used only if workspace too small for wt).
// ---------------------------------------------------------------------------
__global__ __launch_bounds__(256)
void fused_kernel(const float* __restrict__ x, const float* __restrict__ q,
                  const short8* __restrict__ Bg, float* __restrict__ out) {
    __shared__ __align__(16) char S[LDS_TOTAL];

    const int tid  = threadIdx.x;
    const int lane = tid & 63;
    const int wv   = tid >> 6;
    const int b    = blockIdx.x & 15;
    const int t0   = (blockIdx.x >> 4) * 16;

    const int rq = lane & 15;
    const int qq = lane >> 4;
    const float* qrow = q + ((size_t)(t0 + rq) * B_DIM + b) * C_DIM + qq * 8;
    float4 qr[4][2];
#pragma unroll
    for (int s = 0; s < 4; ++s) {
        const int ks = wv + s * 4;
        qr[s][0] = *(const float4*)(qrow + ks * 32);
        qr[s][1] = *(const float4*)(qrow + ks * 32 + 4);
    }
    short8 bfr[16];
#pragma unroll
    for (int ks = 0; ks < 16; ++ks)
        bfr[ks] = Bg[(ks * 4 + wv) * 64 + lane];
    float4 xr[11];
#pragma unroll
    for (int j = 0; j < 11; ++j) {
        const int idx = tid + j * 256;
        const int i   = idx >> 7;
        const int c   = (idx & 127) * 4;
        const int tp  = t0 + i - 3;
        xr[j] = make_float4(0.f, 0.f, 0.f, 0.f);
        if (tp >= 0 && tp < T_DIM)
            xr[j] = *(const float4*)(x + ((size_t)tp * B_DIM + b) * C_DIM + c);
    }

    short8* A8 = (short8*)(S + A_OFF);
#pragma unroll
    for (int s = 0; s < 4; ++s) {
        const int ks = wv + s * 4;
        short8 o;
        o[0] = (short)f2bf(qr[s][0].x); o[1] = (short)f2bf(qr[s][0].y);
        o[2] = (short)f2bf(qr[s][0].z); o[3] = (short)f2bf(qr[s][0].w);
        o[4] = (short)f2bf(qr[s][1].x); o[5] = (short)f2bf(qr[s][1].y);
        o[6] = (short)f2bf(qr[s][1].z); o[7] = (short)f2bf(qr[s][1].w);
        A8[ks * 64 + lane] = o;
    }
    __syncthreads();

    floatx4 acc = (floatx4){0.f, 0.f, 0.f, 0.f};
#pragma unroll
    for (int ks = 0; ks < 16; ++ks) {
        const short8 af = A8[ks * 64 + lane];
        acc = __builtin_amdgcn_mfma_f32_16x16x32_bf16(af, bfr[ks], acc, 0, 0, 0);
    }

    char* XS = S;
#pragma unroll
    for (int j = 0; j < 11; ++j) {
        const int idx = tid + j * 256;
        uint2 p;
        p.x = (unsigned)f2bf(xr[j].x) | ((unsigned)f2bf(xr[j].y) << 16);
        p.y = (unsigned)f2bf(xr[j].z) | ((unsigned)f2bf(xr[j].w) << 16);
        const int a = idx * 8;
        *(uint2*)(XS + swz(a)) = p;
    }
    __syncthreads();

    float* L = (float*)(S + A_OFF);
    const int m = lane & 15;
    const int quad = lane >> 4;
#pragma unroll
    for (int r = 0; r < 4; ++r)
        L[(quad * 4 + r) * 65 + wv * 16 + m] = acc[r];
    __syncthreads();

    float* wt = (float*)(S + WT_OFF);
    if (tid < 128) {
        const int row = tid >> 3, h = tid & 7;
        const float* Lp = L + row * 65 + h * 7;
        float mx = Lp[0];
#pragma unroll
        for (int k = 1; k < 7; ++k) mx = fmaxf(mx, Lp[k]);
        float e[7], sm = 0.f;
#pragma unroll
        for (int k = 0; k < 7; ++k) { e[k] = __expf(Lp[k] - mx); sm += e[k]; }
        const float inv = 1.0f / sm;
#pragma unroll
        for (int k = 0; k < 7; ++k) wt[row * NW + h * 7 + k] = e[k] * inv;
    }
    __syncthreads();

    const int h = lane >> 3;
    const int base_b = lane * 112;
#pragma unroll
    for (int s = 0; s < 4; ++s) {
        const int tt = wv * 4 + s;
        const int tb = tt * 1024 + base_b;
        uint4 xu[7];
#pragma unroll
        for (int i = 0; i < 7; ++i)
            xu[i] = *(const uint4*)(XS + swz(tb + i * 16));
        float xf[56];
#pragma unroll
        for (int i = 0; i < 7; ++i) {
            xf[i * 8 + 0] = bf_lo(xu[i].x); xf[i * 8 + 1] = bf_hi(xu[i].x);
            xf[i * 8 + 2] = bf_lo(xu[i].y); xf[i * 8 + 3] = bf_hi(xu[i].y);
            xf[i * 8 + 4] = bf_lo(xu[i].z); xf[i * 8 + 5] = bf_hi(xu[i].z);
            xf[i * 8 + 6] = bf_lo(xu[i].w); xf[i * 8 + 7] = bf_hi(xu[i].w);
        }
        const float* wp = wt + tt * NW + h * 7;
        float w[7];
#pragma unroll
        for (int k = 0; k < 7; ++k) w[k] = wp[k];
        float a8[8];
#pragma unroll
        for (int r = 0; r < 8; ++r) {
            float sacc = xf[r * 7] * w[0];
#pragma unroll
            for (int k = 1; k < 7; ++k) sacc = fmaf(w[k], xf[r * 7 + k], sacc);
            a8[r] = sacc;
        }
        float* orow = out + ((size_t)(t0 + tt) * B_DIM + b) * C_DIM + lane * 8;
        *(float4*)(orow)     = make_float4(a8[0], a8[1], a8[2], a8[3]);
        *(float4*)(orow + 4) = make_float4(a8[4], a8[5], a8[6], a8[7]);
    }
}

extern "C" void kernel_launch(void* const* d_in, const int* in_sizes, int n_in,
                              void* d_out, int out_size, void* d_ws, size_t ws_size,
                              hipStream_t stream) {
    const float* x = (const float*)d_in[0];
    const float* q = (const float*)d_in[1];
    const float* W = (const float*)d_in[2];
    float* out = (float*)d_out;
    short8* Bg = (short8*)d_ws;   // 64 KB packed bf16 B-fragments

    pack_w<<<16, 256, 0, stream>>>(W, Bg);

    const size_t wt_bytes = (size_t)T_DIM * B_DIM * NW * sizeof(float);  // 7.34 MB
    if (ws_size >= 65536 + wt_bytes) {
        float* wt_g = (float*)((char*)d_ws + 65536);
        weight_kernel<<<(T_DIM / 16) * B_DIM, 256, 0, stream>>>(q, Bg, wt_g);
        conv_kernel<<<(T_DIM / 16) * B_DIM, 256, 0, stream>>>(x, wt_g, out);
    } else {
        fused_kernel<<<(T_DIM / 16) * B_DIM, 256, 0, stream>>>(x, q, Bg, out);
    }
}